// Round 7
// baseline (408.296 us; speedup 1.0000x reference)
//
#include <hip/hip_runtime.h>
#include <hip/hip_bf16.h>

#define NHID 128
#define NGRAPH 512
#define NCLS 10

typedef __attribute__((ext_vector_type(8))) short bf16x8;
typedef __attribute__((ext_vector_type(4))) float f32x4;
typedef __attribute__((ext_vector_type(4))) unsigned int u32x4;

// order-preserving float<->uint encoding for atomicMax-based segment max
__device__ inline unsigned int fenc(float f) {
    unsigned int u = __float_as_uint(f);
    return (u & 0x80000000u) ? ~u : (u | 0x80000000u);
}
__device__ inline float fdec(unsigned int u) {
    u = (u & 0x80000000u) ? (u & 0x7fffffffu) : ~u;
    return __uint_as_float(u);
}
// f32 -> bf16 round-to-nearest-even (finite inputs)
__device__ inline unsigned short f2bf(float f) {
    unsigned int u = __float_as_uint(f);
    return (unsigned short)((u + 0x7fffu + ((u >> 16) & 1u)) >> 16);
}
__device__ inline unsigned int packbf(float lo, float hi) {
    return (unsigned)f2bf(lo) | ((unsigned)f2bf(hi) << 16);
}
__device__ inline float bflo(unsigned int u) { return __uint_as_float(u << 16); }
__device__ inline float bfhi(unsigned int u) { return __uint_as_float(u & 0xffff0000u); }

// merged front kernel: deg atomics | x->bf16 | W transpose | keys zero
__global__ void k_front(const int* __restrict__ dst, int* __restrict__ cnt, int E, int degB,
                        const float* __restrict__ x, unsigned int* __restrict__ xb, int n8, int xB,
                        const float* __restrict__ W1, const float* __restrict__ W2,
                        const float* __restrict__ W3, unsigned short* __restrict__ Wt,
                        unsigned int* __restrict__ keys) {
    int b = blockIdx.x;
    if (b < degB) {
        int e = b * 256 + threadIdx.x;
        if (e < E) atomicAdd(&cnt[dst[e]], 1);
    } else if (b < degB + xB) {
        int i = (b - degB) * 256 + threadIdx.x;
        if (i < n8) {
            const float* p = x + (size_t)i * 8;
            f32x4 a = *reinterpret_cast<const f32x4*>(p);
            f32x4 c = *reinterpret_cast<const f32x4*>(p + 4);
            u32x4 o;
            o[0] = packbf(a[0], a[1]);
            o[1] = packbf(a[2], a[3]);
            o[2] = packbf(c[0], c[1]);
            o[3] = packbf(c[2], c[3]);
            *reinterpret_cast<u32x4*>(xb + (size_t)i * 4) = o;
        }
    } else if (b < degB + xB + 192) {
        int idx = (b - degB - xB) * 256 + threadIdx.x;   // < 3*16384
        int l = idx >> 14;
        int r = idx & 16383;
        const float* W = (l == 0) ? W1 : (l == 1) ? W2 : W3;
        int c = r & 127, k = r >> 7;
        Wt[l * 16384 + c * NHID + k] = f2bf(W[k * NHID + c]);
    } else {
        int i = (b - degB - xB - 192) * 256 + threadIdx.x;
        if (i < NGRAPH * NHID) keys[i] = 0u;
    }
}

// phase 1: per-block (1024-wide) scan of cnt; store chunk-local EXCLUSIVE
// prefix at rowptr[i]; block totals into bsum; dinv as a free rider.
__global__ __launch_bounds__(1024) void k_scan1(const int* __restrict__ cnt,
        float* __restrict__ dinv, int* __restrict__ rowptr,
        int* __restrict__ bsum, int N) {
    __shared__ int lds[1024];
    int t = threadIdx.x;
    int i = blockIdx.x * 1024 + t;
    int v = (i < N) ? cnt[i] : 0;
    if (i < N) dinv[i] = rsqrtf((float)v + 1.0f);
    lds[t] = v;
    __syncthreads();
    for (int off = 1; off < 1024; off <<= 1) {
        int x = (t >= off) ? lds[t - off] : 0;
        __syncthreads();
        lds[t] += x;
        __syncthreads();
    }
    if (i < N) rowptr[i] = lds[t] - v;     // exclusive within chunk
    if (t == 1023) bsum[blockIdx.x] = lds[1023];
}

// phase 2: exclusive scan of nb block sums (nb <= 1024), in place
__global__ __launch_bounds__(1024) void k_scan2(int* __restrict__ bsum, int nb) {
    __shared__ int lds[1024];
    int t = threadIdx.x;
    int v = (t < nb) ? bsum[t] : 0;
    lds[t] = v;
    __syncthreads();
    for (int off = 1; off < 1024; off <<= 1) {
        int x = (t >= off) ? lds[t - off] : 0;
        __syncthreads();
        lds[t] += x;
        __syncthreads();
    }
    if (t < nb) bsum[t] = lds[t] - v;
}

// build packed CSR entries: (src, norm) in one 8B element
__global__ void k_fill(const int* __restrict__ src, const int* __restrict__ dst,
                       const float* __restrict__ dinv, const int* __restrict__ rowptr,
                       const int* __restrict__ bsum, int* __restrict__ cursor,
                       int2* __restrict__ csr, int E) {
    int e = blockIdx.x * blockDim.x + threadIdx.x;
    if (e >= E) return;
    int s = src[e], d = dst[e];
    int pos = rowptr[d] + bsum[d >> 10] + atomicAdd(&cursor[d], 1);
    csr[pos] = make_int2(s, __float_as_int(dinv[s] * dinv[d]));
}

// Sliced aggregation: pass p (0..3) covers feature cols 32p..32p+31 so the
// hot gather table per pass is 3.2 MB -> L2-resident per XCD. Pass is the
// slowest-varying blockIdx dim (dispatch-order locality). 1024-thr blocks,
// 16 waves, one node per wave; 4x16-lane groups x 4 edges per trip, each
// gather one u32 (2 bf16 cols) -> one 64B line per edge per pass.
__global__ __launch_bounds__(1024) void k_aggp(const unsigned int* __restrict__ H32,
        const int2* __restrict__ csr, const int* __restrict__ rowptr,
        const int* __restrict__ bsum, const int* __restrict__ cnt,
        const float* __restrict__ dinv, unsigned int* __restrict__ aggb,
        int N, int nbp) {
    int p = blockIdx.x / nbp;
    int nb = blockIdx.x - p * nbp;
    int w = nb * 16 + (threadIdx.x >> 6);
    if (w >= N) return;
    int lane = threadIdx.x & 63;
    int g = lane >> 4;        // gather group 0..3
    int l16 = lane & 15;      // u32 (col pair) within slice
    int co = p * 16 + l16;    // u32 column in the 64-u32 row
    int beg = rowptr[w] + bsum[w >> 10];
    int deg = cnt[w];
    int end = beg + deg;
    float di = dinv[w];
    unsigned int us = H32[(size_t)w * 64 + co];
    float a0 = 0.f, a1 = 0.f;
    int trips = (deg + 15) >> 4;
    int j = beg + g;
    for (int t = 0; t < trips; ++t, j += 16) {
        int s0 = w, s1 = w, s2 = w, s3 = w;
        float n0 = 0.f, n1 = 0.f, n2 = 0.f, n3 = 0.f;
        if (j < end)      { int2 e2 = csr[j];      s0 = e2.x; n0 = __int_as_float(e2.y); }
        if (j + 4 < end)  { int2 e2 = csr[j + 4];  s1 = e2.x; n1 = __int_as_float(e2.y); }
        if (j + 8 < end)  { int2 e2 = csr[j + 8];  s2 = e2.x; n2 = __int_as_float(e2.y); }
        if (j + 12 < end) { int2 e2 = csr[j + 12]; s3 = e2.x; n3 = __int_as_float(e2.y); }
        unsigned int u0 = H32[(size_t)s0 * 64 + co];
        unsigned int u1 = H32[(size_t)s1 * 64 + co];
        unsigned int u2 = H32[(size_t)s2 * 64 + co];
        unsigned int u3 = H32[(size_t)s3 * 64 + co];
        a0 = fmaf(n0, bflo(u0), a0); a1 = fmaf(n0, bfhi(u0), a1);
        a0 = fmaf(n1, bflo(u1), a0); a1 = fmaf(n1, bfhi(u1), a1);
        a0 = fmaf(n2, bflo(u2), a0); a1 = fmaf(n2, bfhi(u2), a1);
        a0 = fmaf(n3, bflo(u3), a0); a1 = fmaf(n3, bfhi(u3), a1);
    }
    if (g == 0) {
        a0 = fmaf(di * di, bflo(us), a0);
        a1 = fmaf(di * di, bfhi(us), a1);
    }
    a0 += __shfl_xor(a0, 16); a0 += __shfl_xor(a0, 32);
    a1 += __shfl_xor(a1, 16); a1 += __shfl_xor(a1, 32);
    if (g == 0) aggb[(size_t)w * 64 + co] = packbf(a0, a1);
}

// Hb_out = relu(A @ W + b) as bf16; A bf16 [M,128] loaded directly as fragments
__global__ __launch_bounds__(256) void k_gemm(const unsigned short* __restrict__ A,
        const unsigned short* __restrict__ Wt, const float* __restrict__ bias,
        unsigned short* __restrict__ Hb, int M) {
    int wave = threadIdx.x >> 6;
    int lane = threadIdx.x & 63;
    int lr = lane & 15;
    int kq = lane >> 4;
    int r0 = blockIdx.x * 64 + wave * 16;
    f32x4 acc[8];
#pragma unroll
    for (int nt = 0; nt < 8; ++nt) acc[nt] = 0.f;
    int ar = r0 + lr;
    bool arok = ar < M;
#pragma unroll
    for (int kg = 0; kg < 4; ++kg) {
        int kb = kg * 32 + kq * 8;
        bf16x8 af = bf16x8(0);
        if (arok) af = *reinterpret_cast<const bf16x8*>(A + (size_t)ar * NHID + kb);
#pragma unroll
        for (int nt = 0; nt < 8; ++nt) {
            bf16x8 bf = *reinterpret_cast<const bf16x8*>(Wt + (size_t)(nt * 16 + lr) * NHID + kb);
            acc[nt] = __builtin_amdgcn_mfma_f32_16x16x32_bf16(af, bf, acc[nt], 0, 0, 0);
        }
    }
#pragma unroll
    for (int nt = 0; nt < 8; ++nt) {
        int c = nt * 16 + lr;
        float b = bias[c];
#pragma unroll
        for (int e = 0; e < 4; ++e) {
            int r = r0 + kq * 4 + e;
            if (r < M) {
                float v = fmaxf(acc[nt][e] + b, 0.f);
                Hb[(size_t)r * NHID + c] = f2bf(v);
            }
        }
    }
}

// layer-3 GEMM with fused BN (eval) + segment-max epilogue.
__global__ __launch_bounds__(256) void k_gemm_bn(const unsigned short* __restrict__ A,
        const unsigned short* __restrict__ Wt, const float* __restrict__ bias,
        const int* __restrict__ batch, const float* __restrict__ gamma,
        const float* __restrict__ beta, const float* __restrict__ rmean,
        const float* __restrict__ rvar, unsigned int* __restrict__ keys, int M) {
    __shared__ unsigned int smax[64][NHID];   // 32 KB
    __shared__ int bseg[64];
    int tid = threadIdx.x;
    int n0 = blockIdx.x * 64;
    for (int i = tid; i < 64 * NHID; i += 256) ((unsigned int*)smax)[i] = 0u;
    if (tid < 64) {
        int r = n0 + tid;
        bseg[tid] = batch[r < M ? r : M - 1];
    }
    int wave = tid >> 6;
    int lane = tid & 63;
    int lr = lane & 15;
    int kq = lane >> 4;
    int r0 = n0 + wave * 16;
    f32x4 acc[8];
#pragma unroll
    for (int nt = 0; nt < 8; ++nt) acc[nt] = 0.f;
    int ar = r0 + lr;
    bool arok = ar < M;
#pragma unroll
    for (int kg = 0; kg < 4; ++kg) {
        int kb = kg * 32 + kq * 8;
        bf16x8 af = bf16x8(0);
        if (arok) af = *reinterpret_cast<const bf16x8*>(A + (size_t)ar * NHID + kb);
#pragma unroll
        for (int nt = 0; nt < 8; ++nt) {
            bf16x8 bf = *reinterpret_cast<const bf16x8*>(Wt + (size_t)(nt * 16 + lr) * NHID + kb);
            acc[nt] = __builtin_amdgcn_mfma_f32_16x16x32_bf16(af, bf, acc[nt], 0, 0, 0);
        }
    }
    __syncthreads();   // smax/bseg init complete
    int glo = bseg[0];
#pragma unroll
    for (int nt = 0; nt < 8; ++nt) {
        int c = nt * 16 + lr;
        float b = bias[c];
        float sc = gamma[c] * rsqrtf(rvar[c] + 1e-5f);
        float sh = beta[c] - rmean[c] * sc;
#pragma unroll
        for (int e = 0; e < 4; ++e) {
            int rr = wave * 16 + kq * 4 + e;
            if (n0 + rr < M) {
                float v = fmaxf(acc[nt][e] + b, 0.f);
                float y = fmaf(v, sc, sh);
                atomicMax(&smax[bseg[rr] - glo][c], fenc(y));
            }
        }
    }
    __syncthreads();
    int last = M - 1 - n0;
    if (last > 63) last = 63;
    int span = bseg[last] - glo + 1;
    for (int i = tid; i < span * NHID; i += 256) {
        unsigned int v = ((unsigned int*)smax)[i];
        if (v) atomicMax(&keys[(size_t)(glo + (i >> 7)) * NHID + (i & 127)], v);
    }
}

// fused head: decode keys -> relu(G@lw1+lb1) -> relu(@lw2+lb2) -> @lw3+lb3
__global__ __launch_bounds__(128) void k_head(const unsigned int* __restrict__ keys,
        const float* __restrict__ lw1, const float* __restrict__ lb1,
        const float* __restrict__ lw2, const float* __restrict__ lb2,
        const float* __restrict__ lw3, const float* __restrict__ lb3,
        float* __restrict__ out) {
    __shared__ float g0[NHID], g1[NHID], g2[64];
    int r = blockIdx.x;
    int t = threadIdx.x;
    unsigned int u = keys[(size_t)r * NHID + t];
    g0[t] = (u == 0u) ? -3.0e38f : fdec(u);
    __syncthreads();
    float acc = lb1[t];
#pragma unroll 8
    for (int k = 0; k < NHID; ++k) acc = fmaf(g0[k], lw1[k * NHID + t], acc);
    g1[t] = fmaxf(acc, 0.f);
    __syncthreads();
    if (t < 64) {
        acc = lb2[t];
#pragma unroll 8
        for (int k = 0; k < NHID; ++k) acc = fmaf(g1[k], lw2[k * 64 + t], acc);
        g2[t] = fmaxf(acc, 0.f);
    }
    __syncthreads();
    if (t < NCLS) {
        acc = lb3[t];
#pragma unroll 8
        for (int k = 0; k < 64; ++k) acc = fmaf(g2[k], lw3[k * NCLS + t], acc);
        out[(size_t)r * NCLS + t] = acc;
    }
}

extern "C" void kernel_launch(void* const* d_in, const int* in_sizes, int n_in,
                              void* d_out, int out_size, void* d_ws, size_t ws_size,
                              hipStream_t stream) {
    const float* x     = (const float*)d_in[0];
    const int*   ei    = (const int*)d_in[1];
    const int*   batch = (const int*)d_in[2];
    const float* W1 = (const float*)d_in[3];
    const float* b1 = (const float*)d_in[4];
    const float* W2 = (const float*)d_in[5];
    const float* b2 = (const float*)d_in[6];
    const float* W3 = (const float*)d_in[7];
    const float* b3 = (const float*)d_in[8];
    const float* gamma = (const float*)d_in[9];
    const float* beta  = (const float*)d_in[10];
    const float* rmean = (const float*)d_in[11];
    const float* rvar  = (const float*)d_in[12];
    const float* lw1 = (const float*)d_in[13];
    const float* lb1 = (const float*)d_in[14];
    const float* lw2 = (const float*)d_in[15];
    const float* lb2 = (const float*)d_in[16];
    const float* lw3 = (const float*)d_in[17];
    const float* lb3 = (const float*)d_in[18];

    const int N = in_sizes[2];
    const int E = in_sizes[1] / 2;
    const int* src = ei;
    const int* dst = ei + E;

    char* ws = (char*)d_ws;
    size_t off = 0;
    auto alloc = [&](size_t bytes) {
        char* p = ws + off;
        off += (bytes + 255) & ~(size_t)255;
        return p;
    };
    int*   cnt     = (int*)  alloc((size_t)N * 8);     // cnt[N] + cursor[N], one memset
    int*   cursor  = cnt + N;
    int*   rowptr  = (int*)  alloc((size_t)N * 4);
    int*   bsum    = (int*)  alloc(1024 * 4);
    float* dinv    = (float*)alloc((size_t)N * 4);
    int2*  csr     = (int2*) alloc((size_t)E * 8);
    unsigned int* xb   = (unsigned int*)alloc((size_t)N * NHID * 2);
    unsigned int* aggb = (unsigned int*)alloc((size_t)N * NHID * 2);
    unsigned int* Hb   = (unsigned int*)alloc((size_t)N * NHID * 2);
    unsigned short* Wt = (unsigned short*)alloc((size_t)3 * NHID * NHID * 2);
    unsigned int* keys = (unsigned int*)alloc((size_t)NGRAPH * NHID * 4);
    (void)ws_size; (void)n_in; (void)out_size;

    hipMemsetAsync(cnt, 0, (size_t)N * 8, stream);

    int degB = (E + 255) / 256;
    int n8 = N * 16;
    int xB = (n8 + 255) / 256;
    int frontB = degB + xB + 192 + (NGRAPH * NHID + 255) / 256;
    k_front<<<frontB, 256, 0, stream>>>(dst, cnt, E, degB, x, xb, n8, xB,
                                        W1, W2, W3, Wt, keys);
    int nb1 = (N + 1023) / 1024;
    k_scan1<<<nb1, 1024, 0, stream>>>(cnt, dinv, rowptr, bsum, N);
    k_scan2<<<1, 1024, 0, stream>>>(bsum, nb1);
    k_fill<<<degB, 256, 0, stream>>>(src, dst, dinv, rowptr, bsum, cursor, csr, E);

    int nbp = (N + 15) / 16;           // node-blocks per pass (16 nodes/block)
    int agrid = 4 * nbp;               // pass-major: slice locality in L2
    int gb = (N + 63) / 64;
    k_aggp<<<agrid, 1024, 0, stream>>>(xb, csr, rowptr, bsum, cnt, dinv, aggb, N, nbp);
    k_gemm<<<gb, 256, 0, stream>>>((const unsigned short*)aggb, Wt, b1, (unsigned short*)Hb, N);
    k_aggp<<<agrid, 1024, 0, stream>>>(Hb, csr, rowptr, bsum, cnt, dinv, aggb, N, nbp);
    k_gemm<<<gb, 256, 0, stream>>>((const unsigned short*)aggb, Wt + 16384, b2, (unsigned short*)Hb, N);
    k_aggp<<<agrid, 1024, 0, stream>>>(Hb, csr, rowptr, bsum, cnt, dinv, aggb, N, nbp);
    k_gemm_bn<<<gb, 256, 0, stream>>>((const unsigned short*)aggb, Wt + 32768, b3,
                                      batch, gamma, beta, rmean, rvar, keys, N);

    k_head<<<NGRAPH, 128, 0, stream>>>(keys, lw1, lb1, lw2, lb2, lw3, lb3, (float*)d_out);
}

// Round 8
// 248.939 us; speedup vs baseline: 1.6401x; 1.6401x over previous
//
#include <hip/hip_runtime.h>
#include <hip/hip_bf16.h>

#define NHID 128
#define NGRAPH 512
#define NCLS 10

typedef __attribute__((ext_vector_type(8))) short bf16x8;
typedef __attribute__((ext_vector_type(4))) float f32x4;
typedef __attribute__((ext_vector_type(4))) unsigned int u32x4;

// order-preserving float<->uint encoding for atomicMax-based segment max
__device__ inline unsigned int fenc(float f) {
    unsigned int u = __float_as_uint(f);
    return (u & 0x80000000u) ? ~u : (u | 0x80000000u);
}
__device__ inline float fdec(unsigned int u) {
    u = (u & 0x80000000u) ? (u & 0x7fffffffu) : ~u;
    return __uint_as_float(u);
}
// f32 -> bf16 round-to-nearest-even (finite inputs)
__device__ inline unsigned short f2bf(float f) {
    unsigned int u = __float_as_uint(f);
    return (unsigned short)((u + 0x7fffu + ((u >> 16) & 1u)) >> 16);
}
__device__ inline unsigned int packbf(float lo, float hi) {
    return (unsigned)f2bf(lo) | ((unsigned)f2bf(hi) << 16);
}

// merged front kernel: deg atomics | x->bf16 | W transpose | keys zero
__global__ void k_front(const int* __restrict__ dst, int* __restrict__ cnt, int E, int degB,
                        const float* __restrict__ x, unsigned int* __restrict__ xb, int n8, int xB,
                        const float* __restrict__ W1, const float* __restrict__ W2,
                        const float* __restrict__ W3, unsigned short* __restrict__ Wt,
                        unsigned int* __restrict__ keys) {
    int b = blockIdx.x;
    if (b < degB) {
        int e = b * 256 + threadIdx.x;
        if (e < E) atomicAdd(&cnt[dst[e]], 1);
    } else if (b < degB + xB) {
        int i = (b - degB) * 256 + threadIdx.x;
        if (i < n8) {
            const float* p = x + (size_t)i * 8;
            f32x4 a = *reinterpret_cast<const f32x4*>(p);
            f32x4 c = *reinterpret_cast<const f32x4*>(p + 4);
            u32x4 o;
            o[0] = packbf(a[0], a[1]);
            o[1] = packbf(a[2], a[3]);
            o[2] = packbf(c[0], c[1]);
            o[3] = packbf(c[2], c[3]);
            *reinterpret_cast<u32x4*>(xb + (size_t)i * 4) = o;
        }
    } else if (b < degB + xB + 192) {
        int idx = (b - degB - xB) * 256 + threadIdx.x;   // < 3*16384
        int l = idx >> 14;
        int r = idx & 16383;
        const float* W = (l == 0) ? W1 : (l == 1) ? W2 : W3;
        int c = r & 127, k = r >> 7;
        Wt[l * 16384 + c * NHID + k] = f2bf(W[k * NHID + c]);
    } else {
        int i = (b - degB - xB - 192) * 256 + threadIdx.x;
        if (i < NGRAPH * NHID) keys[i] = 0u;
    }
}

// phase 1: per-block (1024-wide) scan of cnt; store chunk-local EXCLUSIVE
// prefix at rowptr[i]; block totals into bsum; dinv as a free rider.
__global__ __launch_bounds__(1024) void k_scan1(const int* __restrict__ cnt,
        float* __restrict__ dinv, int* __restrict__ rowptr,
        int* __restrict__ bsum, int N) {
    __shared__ int lds[1024];
    int t = threadIdx.x;
    int i = blockIdx.x * 1024 + t;
    int v = (i < N) ? cnt[i] : 0;
    if (i < N) dinv[i] = rsqrtf((float)v + 1.0f);
    lds[t] = v;
    __syncthreads();
    for (int off = 1; off < 1024; off <<= 1) {
        int x = (t >= off) ? lds[t - off] : 0;
        __syncthreads();
        lds[t] += x;
        __syncthreads();
    }
    if (i < N) rowptr[i] = lds[t] - v;     // exclusive within chunk
    if (t == 1023) bsum[blockIdx.x] = lds[1023];
}

// phase 2: exclusive scan of nb block sums (nb <= 1024), in place
__global__ __launch_bounds__(1024) void k_scan2(int* __restrict__ bsum, int nb) {
    __shared__ int lds[1024];
    int t = threadIdx.x;
    int v = (t < nb) ? bsum[t] : 0;
    lds[t] = v;
    __syncthreads();
    for (int off = 1; off < 1024; off <<= 1) {
        int x = (t >= off) ? lds[t - off] : 0;
        __syncthreads();
        lds[t] += x;
        __syncthreads();
    }
    if (t < nb) bsum[t] = lds[t] - v;
}

// build CSR src list (4B/edge); norms are computed in the gather
__global__ void k_fill(const int* __restrict__ src, const int* __restrict__ dst,
                       const int* __restrict__ rowptr, const int* __restrict__ bsum,
                       int* __restrict__ cursor, int* __restrict__ csr_src, int E) {
    int e = blockIdx.x * blockDim.x + threadIdx.x;
    if (e >= E) return;
    int s = src[e], d = dst[e];
    int pos = rowptr[d] + bsum[d >> 10] + atomicAdd(&cursor[d], 1);
    csr_src[pos] = s;
}

__device__ inline void fma8(const u32x4& u, float nw, float* a) {
#pragma unroll
    for (int q = 0; q < 4; ++q) {
        a[2 * q]     = fmaf(nw, __uint_as_float(u[q] << 16), a[2 * q]);
        a[2 * q + 1] = fmaf(nw, __uint_as_float(u[q] & 0xffff0000u), a[2 * q + 1]);
    }
}

// one wave per node, 4 x 16-lane gather groups, bf16 input rows (256B each).
// Per trip, group g handles FOUR edges (j, j+4, j+8, j+12): 16 independent
// row-gathers in flight per wave; deg<=16 completes in one trip.
// norm = dinv[src]*dinv[w] computed here (dinv is L2-resident, broadcast).
// Cross-group combine via shfl_xor(16),(32); group 0 writes bf16 row.
__global__ __launch_bounds__(256) void k_agg(const unsigned int* __restrict__ Hb,
        const int* __restrict__ csr_src, const int* __restrict__ rowptr,
        const int* __restrict__ bsum, const int* __restrict__ cnt,
        const float* __restrict__ dinv, unsigned int* __restrict__ aggb, int N) {
    int w = (blockIdx.x * 256 + threadIdx.x) >> 6;
    if (w >= N) return;
    int lane = threadIdx.x & 63;
    int g = lane >> 4;        // gather group 0..3
    int l16 = lane & 15;      // 16B chunk within row
    float diw = dinv[w];
    u32x4 us = reinterpret_cast<const u32x4*>(Hb + (size_t)w * (NHID / 2))[l16];
    float a[8];
#pragma unroll
    for (int e = 0; e < 8; ++e) a[e] = 0.f;
    int beg = rowptr[w] + bsum[w >> 10];
    int deg = cnt[w];
    int end = beg + deg;
    int trips = (deg + 15) >> 4;
    int j = beg + g;
    for (int t = 0; t < trips; ++t, j += 16) {
        int s0 = w, s1 = w, s2 = w, s3 = w;
        if (j < end)      s0 = csr_src[j];
        if (j + 4 < end)  s1 = csr_src[j + 4];
        if (j + 8 < end)  s2 = csr_src[j + 8];
        if (j + 12 < end) s3 = csr_src[j + 12];
        float n0 = (j < end)      ? dinv[s0] * diw : 0.f;
        float n1 = (j + 4 < end)  ? dinv[s1] * diw : 0.f;
        float n2 = (j + 8 < end)  ? dinv[s2] * diw : 0.f;
        float n3 = (j + 12 < end) ? dinv[s3] * diw : 0.f;
        u32x4 u0 = reinterpret_cast<const u32x4*>(Hb + (size_t)s0 * (NHID / 2))[l16];
        u32x4 u1 = reinterpret_cast<const u32x4*>(Hb + (size_t)s1 * (NHID / 2))[l16];
        u32x4 u2 = reinterpret_cast<const u32x4*>(Hb + (size_t)s2 * (NHID / 2))[l16];
        u32x4 u3 = reinterpret_cast<const u32x4*>(Hb + (size_t)s3 * (NHID / 2))[l16];
        fma8(u0, n0, a);
        fma8(u1, n1, a);
        fma8(u2, n2, a);
        fma8(u3, n3, a);
    }
    // self-loop on group 0
    if (g == 0) fma8(us, diw * diw, a);
    // combine the 4 groups
#pragma unroll
    for (int e = 0; e < 8; ++e) {
        a[e] += __shfl_xor(a[e], 16);
        a[e] += __shfl_xor(a[e], 32);
    }
    if (g == 0) {
        u32x4 o;
        o[0] = packbf(a[0], a[1]);
        o[1] = packbf(a[2], a[3]);
        o[2] = packbf(a[4], a[5]);
        o[3] = packbf(a[6], a[7]);
        *reinterpret_cast<u32x4*>(aggb + (size_t)w * (NHID / 2) + l16 * 4) = o;
    }
}

// Hb_out = relu(A @ W + b) as bf16; A bf16 [M,128] loaded directly as fragments
__global__ __launch_bounds__(256) void k_gemm(const unsigned short* __restrict__ A,
        const unsigned short* __restrict__ Wt, const float* __restrict__ bias,
        unsigned short* __restrict__ Hb, int M) {
    int wave = threadIdx.x >> 6;
    int lane = threadIdx.x & 63;
    int lr = lane & 15;
    int kq = lane >> 4;
    int r0 = blockIdx.x * 64 + wave * 16;
    f32x4 acc[8];
#pragma unroll
    for (int nt = 0; nt < 8; ++nt) acc[nt] = 0.f;
    int ar = r0 + lr;
    bool arok = ar < M;
#pragma unroll
    for (int kg = 0; kg < 4; ++kg) {
        int kb = kg * 32 + kq * 8;
        bf16x8 af = bf16x8(0);
        if (arok) af = *reinterpret_cast<const bf16x8*>(A + (size_t)ar * NHID + kb);
#pragma unroll
        for (int nt = 0; nt < 8; ++nt) {
            bf16x8 bf = *reinterpret_cast<const bf16x8*>(Wt + (size_t)(nt * 16 + lr) * NHID + kb);
            acc[nt] = __builtin_amdgcn_mfma_f32_16x16x32_bf16(af, bf, acc[nt], 0, 0, 0);
        }
    }
#pragma unroll
    for (int nt = 0; nt < 8; ++nt) {
        int c = nt * 16 + lr;
        float b = bias[c];
#pragma unroll
        for (int e = 0; e < 4; ++e) {
            int r = r0 + kq * 4 + e;
            if (r < M) {
                float v = fmaxf(acc[nt][e] + b, 0.f);
                Hb[(size_t)r * NHID + c] = f2bf(v);
            }
        }
    }
}

// layer-3 GEMM with fused BN (eval) + segment-max epilogue.
__global__ __launch_bounds__(256) void k_gemm_bn(const unsigned short* __restrict__ A,
        const unsigned short* __restrict__ Wt, const float* __restrict__ bias,
        const int* __restrict__ batch, const float* __restrict__ gamma,
        const float* __restrict__ beta, const float* __restrict__ rmean,
        const float* __restrict__ rvar, unsigned int* __restrict__ keys, int M) {
    __shared__ unsigned int smax[64][NHID];   // 32 KB
    __shared__ int bseg[64];
    int tid = threadIdx.x;
    int n0 = blockIdx.x * 64;
    for (int i = tid; i < 64 * NHID; i += 256) ((unsigned int*)smax)[i] = 0u;
    if (tid < 64) {
        int r = n0 + tid;
        bseg[tid] = batch[r < M ? r : M - 1];
    }
    int wave = tid >> 6;
    int lane = tid & 63;
    int lr = lane & 15;
    int kq = lane >> 4;
    int r0 = n0 + wave * 16;
    f32x4 acc[8];
#pragma unroll
    for (int nt = 0; nt < 8; ++nt) acc[nt] = 0.f;
    int ar = r0 + lr;
    bool arok = ar < M;
#pragma unroll
    for (int kg = 0; kg < 4; ++kg) {
        int kb = kg * 32 + kq * 8;
        bf16x8 af = bf16x8(0);
        if (arok) af = *reinterpret_cast<const bf16x8*>(A + (size_t)ar * NHID + kb);
#pragma unroll
        for (int nt = 0; nt < 8; ++nt) {
            bf16x8 bf = *reinterpret_cast<const bf16x8*>(Wt + (size_t)(nt * 16 + lr) * NHID + kb);
            acc[nt] = __builtin_amdgcn_mfma_f32_16x16x32_bf16(af, bf, acc[nt], 0, 0, 0);
        }
    }
    __syncthreads();   // smax/bseg init complete
    int glo = bseg[0];
#pragma unroll
    for (int nt = 0; nt < 8; ++nt) {
        int c = nt * 16 + lr;
        float b = bias[c];
        float sc = gamma[c] * rsqrtf(rvar[c] + 1e-5f);
        float sh = beta[c] - rmean[c] * sc;
#pragma unroll
        for (int e = 0; e < 4; ++e) {
            int rr = wave * 16 + kq * 4 + e;
            if (n0 + rr < M) {
                float v = fmaxf(acc[nt][e] + b, 0.f);
                float y = fmaf(v, sc, sh);
                atomicMax(&smax[bseg[rr] - glo][c], fenc(y));
            }
        }
    }
    __syncthreads();
    int last = M - 1 - n0;
    if (last > 63) last = 63;
    int span = bseg[last] - glo + 1;
    for (int i = tid; i < span * NHID; i += 256) {
        unsigned int v = ((unsigned int*)smax)[i];
        if (v) atomicMax(&keys[(size_t)(glo + (i >> 7)) * NHID + (i & 127)], v);
    }
}

// fused head: decode keys -> relu(G@lw1+lb1) -> relu(@lw2+lb2) -> @lw3+lb3
__global__ __launch_bounds__(128) void k_head(const unsigned int* __restrict__ keys,
        const float* __restrict__ lw1, const float* __restrict__ lb1,
        const float* __restrict__ lw2, const float* __restrict__ lb2,
        const float* __restrict__ lw3, const float* __restrict__ lb3,
        float* __restrict__ out) {
    __shared__ float g0[NHID], g1[NHID], g2[64];
    int r = blockIdx.x;
    int t = threadIdx.x;
    unsigned int u = keys[(size_t)r * NHID + t];
    g0[t] = (u == 0u) ? -3.0e38f : fdec(u);
    __syncthreads();
    float acc = lb1[t];
#pragma unroll 8
    for (int k = 0; k < NHID; ++k) acc = fmaf(g0[k], lw1[k * NHID + t], acc);
    g1[t] = fmaxf(acc, 0.f);
    __syncthreads();
    if (t < 64) {
        acc = lb2[t];
#pragma unroll 8
        for (int k = 0; k < NHID; ++k) acc = fmaf(g1[k], lw2[k * 64 + t], acc);
        g2[t] = fmaxf(acc, 0.f);
    }
    __syncthreads();
    if (t < NCLS) {
        acc = lb3[t];
#pragma unroll 8
        for (int k = 0; k < 64; ++k) acc = fmaf(g2[k], lw3[k * NCLS + t], acc);
        out[(size_t)r * NCLS + t] = acc;
    }
}

extern "C" void kernel_launch(void* const* d_in, const int* in_sizes, int n_in,
                              void* d_out, int out_size, void* d_ws, size_t ws_size,
                              hipStream_t stream) {
    const float* x     = (const float*)d_in[0];
    const int*   ei    = (const int*)d_in[1];
    const int*   batch = (const int*)d_in[2];
    const float* W1 = (const float*)d_in[3];
    const float* b1 = (const float*)d_in[4];
    const float* W2 = (const float*)d_in[5];
    const float* b2 = (const float*)d_in[6];
    const float* W3 = (const float*)d_in[7];
    const float* b3 = (const float*)d_in[8];
    const float* gamma = (const float*)d_in[9];
    const float* beta  = (const float*)d_in[10];
    const float* rmean = (const float*)d_in[11];
    const float* rvar  = (const float*)d_in[12];
    const float* lw1 = (const float*)d_in[13];
    const float* lb1 = (const float*)d_in[14];
    const float* lw2 = (const float*)d_in[15];
    const float* lb2 = (const float*)d_in[16];
    const float* lw3 = (const float*)d_in[17];
    const float* lb3 = (const float*)d_in[18];

    const int N = in_sizes[2];
    const int E = in_sizes[1] / 2;
    const int* src = ei;
    const int* dst = ei + E;

    char* ws = (char*)d_ws;
    size_t off = 0;
    auto alloc = [&](size_t bytes) {
        char* p = ws + off;
        off += (bytes + 255) & ~(size_t)255;
        return p;
    };
    int*   cnt     = (int*)  alloc((size_t)N * 8);     // cnt[N] + cursor[N], one memset
    int*   cursor  = cnt + N;
    int*   rowptr  = (int*)  alloc((size_t)N * 4);
    int*   bsum    = (int*)  alloc(1024 * 4);
    float* dinv    = (float*)alloc((size_t)N * 4);
    int*   csr_src = (int*)  alloc((size_t)E * 4);
    unsigned int* xb   = (unsigned int*)alloc((size_t)N * NHID * 2);
    unsigned int* aggb = (unsigned int*)alloc((size_t)N * NHID * 2);
    unsigned int* Hb   = (unsigned int*)alloc((size_t)N * NHID * 2);
    unsigned short* Wt = (unsigned short*)alloc((size_t)3 * NHID * NHID * 2);
    unsigned int* keys = (unsigned int*)alloc((size_t)NGRAPH * NHID * 4);
    (void)ws_size; (void)n_in; (void)out_size;

    hipMemsetAsync(cnt, 0, (size_t)N * 8, stream);

    int degB = (E + 255) / 256;
    int n8 = N * 16;
    int xB = (n8 + 255) / 256;
    int frontB = degB + xB + 192 + (NGRAPH * NHID + 255) / 256;
    k_front<<<frontB, 256, 0, stream>>>(dst, cnt, E, degB, x, xb, n8, xB,
                                        W1, W2, W3, Wt, keys);
    int nb1 = (N + 1023) / 1024;
    k_scan1<<<nb1, 1024, 0, stream>>>(cnt, dinv, rowptr, bsum, N);
    k_scan2<<<1, 1024, 0, stream>>>(bsum, nb1);
    k_fill<<<degB, 256, 0, stream>>>(src, dst, rowptr, bsum, cursor, csr_src, E);

    int ab = ((size_t)N * 64 + 255) / 256;   // one wave per node
    int gb = (N + 63) / 64;
    k_agg<<<ab, 256, 0, stream>>>(xb, csr_src, rowptr, bsum, cnt, dinv, aggb, N);
    k_gemm<<<gb, 256, 0, stream>>>((const unsigned short*)aggb, Wt, b1, (unsigned short*)Hb, N);
    k_agg<<<ab, 256, 0, stream>>>(Hb, csr_src, rowptr, bsum, cnt, dinv, aggb, N);
    k_gemm<<<gb, 256, 0, stream>>>((const unsigned short*)aggb, Wt + 16384, b2, (unsigned short*)Hb, N);
    k_agg<<<ab, 256, 0, stream>>>(Hb, csr_src, rowptr, bsum, cnt, dinv, aggb, N);
    k_gemm_bn<<<gb, 256, 0, stream>>>((const unsigned short*)aggb, Wt + 32768, b3,
                                      batch, gamma, beta, rmean, rvar, keys, N);

    k_head<<<NGRAPH, 128, 0, stream>>>(keys, lw1, lb1, lw2, lb2, lw3, lb3, (float*)d_out);
}

// Round 9
// 234.881 us; speedup vs baseline: 1.7383x; 1.0599x over previous
//
#include <hip/hip_runtime.h>
#include <hip/hip_bf16.h>

#define NHID 128
#define NGRAPH 512
#define NCLS 10

typedef __attribute__((ext_vector_type(8))) short bf16x8;
typedef __attribute__((ext_vector_type(4))) float f32x4;
typedef __attribute__((ext_vector_type(4))) unsigned int u32x4;

// order-preserving float<->uint encoding for atomicMax-based segment max
__device__ inline unsigned int fenc(float f) {
    unsigned int u = __float_as_uint(f);
    return (u & 0x80000000u) ? ~u : (u | 0x80000000u);
}
__device__ inline float fdec(unsigned int u) {
    u = (u & 0x80000000u) ? (u & 0x7fffffffu) : ~u;
    return __uint_as_float(u);
}
// f32 -> bf16 round-to-nearest-even (finite inputs)
__device__ inline unsigned short f2bf(float f) {
    unsigned int u = __float_as_uint(f);
    return (unsigned short)((u + 0x7fffu + ((u >> 16) & 1u)) >> 16);
}
__device__ inline unsigned int packbf(float lo, float hi) {
    return (unsigned)f2bf(lo) | ((unsigned)f2bf(hi) << 16);
}

// merged front kernel: deg atomics | x->bf16 | W transpose | keys zero
__global__ void k_front(const int* __restrict__ dst, int* __restrict__ cnt, int E, int degB,
                        const float* __restrict__ x, unsigned int* __restrict__ xb, int n8, int xB,
                        const float* __restrict__ W1, const float* __restrict__ W2,
                        const float* __restrict__ W3, unsigned short* __restrict__ Wt,
                        unsigned int* __restrict__ keys) {
    int b = blockIdx.x;
    if (b < degB) {
        int e = b * 256 + threadIdx.x;
        if (e < E) atomicAdd(&cnt[dst[e]], 1);
    } else if (b < degB + xB) {
        int i = (b - degB) * 256 + threadIdx.x;
        if (i < n8) {
            const float* p = x + (size_t)i * 8;
            f32x4 a = *reinterpret_cast<const f32x4*>(p);
            f32x4 c = *reinterpret_cast<const f32x4*>(p + 4);
            u32x4 o;
            o[0] = packbf(a[0], a[1]);
            o[1] = packbf(a[2], a[3]);
            o[2] = packbf(c[0], c[1]);
            o[3] = packbf(c[2], c[3]);
            *reinterpret_cast<u32x4*>(xb + (size_t)i * 4) = o;
        }
    } else if (b < degB + xB + 192) {
        int idx = (b - degB - xB) * 256 + threadIdx.x;   // < 3*16384
        int l = idx >> 14;
        int r = idx & 16383;
        const float* W = (l == 0) ? W1 : (l == 1) ? W2 : W3;
        int c = r & 127, k = r >> 7;
        Wt[l * 16384 + c * NHID + k] = f2bf(W[k * NHID + c]);
    } else {
        int i = (b - degB - xB - 192) * 256 + threadIdx.x;
        if (i < NGRAPH * NHID) keys[i] = 0u;
    }
}

// phase 1: per-block (1024-wide) scan of cnt; store chunk-local EXCLUSIVE
// prefix at rowptr[i]; block totals into bsum; dinv as a free rider.
__global__ __launch_bounds__(1024) void k_scan1(const int* __restrict__ cnt,
        float* __restrict__ dinv, int* __restrict__ rowptr,
        int* __restrict__ bsum, int N) {
    __shared__ int lds[1024];
    int t = threadIdx.x;
    int i = blockIdx.x * 1024 + t;
    int v = (i < N) ? cnt[i] : 0;
    if (i < N) dinv[i] = rsqrtf((float)v + 1.0f);
    lds[t] = v;
    __syncthreads();
    for (int off = 1; off < 1024; off <<= 1) {
        int x = (t >= off) ? lds[t - off] : 0;
        __syncthreads();
        lds[t] += x;
        __syncthreads();
    }
    if (i < N) rowptr[i] = lds[t] - v;     // exclusive within chunk
    if (t == 1023) bsum[blockIdx.x] = lds[1023];
}

// phase 2: exclusive scan of nb block sums (nb <= 1024), in place
__global__ __launch_bounds__(1024) void k_scan2(int* __restrict__ bsum, int nb) {
    __shared__ int lds[1024];
    int t = threadIdx.x;
    int v = (t < nb) ? bsum[t] : 0;
    lds[t] = v;
    __syncthreads();
    for (int off = 1; off < 1024; off <<= 1) {
        int x = (t >= off) ? lds[t - off] : 0;
        __syncthreads();
        lds[t] += x;
        __syncthreads();
    }
    if (t < nb) bsum[t] = lds[t] - v;
}

// build CSR src list (4B/edge); norms are computed in the gather
__global__ void k_fill(const int* __restrict__ src, const int* __restrict__ dst,
                       const int* __restrict__ rowptr, const int* __restrict__ bsum,
                       int* __restrict__ cursor, int* __restrict__ csr_src, int E) {
    int e = blockIdx.x * blockDim.x + threadIdx.x;
    if (e >= E) return;
    int s = src[e], d = dst[e];
    int pos = rowptr[d] + bsum[d >> 10] + atomicAdd(&cursor[d], 1);
    csr_src[pos] = s;
}

__device__ inline void fma8(const u32x4& u, float nw, float* a) {
#pragma unroll
    for (int q = 0; q < 4; ++q) {
        a[2 * q]     = fmaf(nw, __uint_as_float(u[q] << 16), a[2 * q]);
        a[2 * q + 1] = fmaf(nw, __uint_as_float(u[q] & 0xffff0000u), a[2 * q + 1]);
    }
}

// Fused aggregate+GEMM, TLP-preserving: 1024-thr block = 16 waves, ONE WAVE
// PER NODE for the gather (identical to k_agg), rows -> LDS tile (stride 68
// u32 = 272B), one barrier, then waves 0..7 each compute one 16-col MFMA
// tile of the row-local GEMM: Hout = relu(agg @ W + b) as bf16.
__global__ __launch_bounds__(1024) void k_agg_gemm(const unsigned int* __restrict__ Hin,
        const int* __restrict__ csr_src, const int* __restrict__ rowptr,
        const int* __restrict__ bsum, const int* __restrict__ cnt,
        const float* __restrict__ dinv, const unsigned short* __restrict__ Wt,
        const float* __restrict__ bias, unsigned short* __restrict__ Hout, int N) {
    __shared__ unsigned int lds[16][68];
    int wv = threadIdx.x >> 6;
    int lane = threadIdx.x & 63;
    int g = lane >> 4;        // gather group 0..3
    int l16 = lane & 15;      // 16B chunk within row
    int w = blockIdx.x * 16 + wv;
    if (w < N) {
        float diw = dinv[w];
        u32x4 us = reinterpret_cast<const u32x4*>(Hin + (size_t)w * (NHID / 2))[l16];
        float a[8];
#pragma unroll
        for (int e = 0; e < 8; ++e) a[e] = 0.f;
        int beg = rowptr[w] + bsum[w >> 10];
        int deg = cnt[w];
        int end = beg + deg;
        int trips = (deg + 15) >> 4;
        int j = beg + g;
        for (int t = 0; t < trips; ++t, j += 16) {
            int s0 = w, s1 = w, s2 = w, s3 = w;
            if (j < end)      s0 = csr_src[j];
            if (j + 4 < end)  s1 = csr_src[j + 4];
            if (j + 8 < end)  s2 = csr_src[j + 8];
            if (j + 12 < end) s3 = csr_src[j + 12];
            float n0 = (j < end)      ? dinv[s0] * diw : 0.f;
            float n1 = (j + 4 < end)  ? dinv[s1] * diw : 0.f;
            float n2 = (j + 8 < end)  ? dinv[s2] * diw : 0.f;
            float n3 = (j + 12 < end) ? dinv[s3] * diw : 0.f;
            u32x4 u0 = reinterpret_cast<const u32x4*>(Hin + (size_t)s0 * (NHID / 2))[l16];
            u32x4 u1 = reinterpret_cast<const u32x4*>(Hin + (size_t)s1 * (NHID / 2))[l16];
            u32x4 u2 = reinterpret_cast<const u32x4*>(Hin + (size_t)s2 * (NHID / 2))[l16];
            u32x4 u3 = reinterpret_cast<const u32x4*>(Hin + (size_t)s3 * (NHID / 2))[l16];
            fma8(u0, n0, a);
            fma8(u1, n1, a);
            fma8(u2, n2, a);
            fma8(u3, n3, a);
        }
        if (g == 0) fma8(us, diw * diw, a);
#pragma unroll
        for (int e = 0; e < 8; ++e) {
            a[e] += __shfl_xor(a[e], 16);
            a[e] += __shfl_xor(a[e], 32);
        }
        if (g == 0) {
            u32x4 o;
            o[0] = packbf(a[0], a[1]);
            o[1] = packbf(a[2], a[3]);
            o[2] = packbf(a[4], a[5]);
            o[3] = packbf(a[6], a[7]);
            *reinterpret_cast<u32x4*>(&lds[wv][l16 * 4]) = o;
        }
    } else if (g == 0) {
        u32x4 z = {0u, 0u, 0u, 0u};
        *reinterpret_cast<u32x4*>(&lds[wv][l16 * 4]) = z;
    }
    __syncthreads();
    if (wv < 8) {
        // wave wv computes output cols wv*16 .. wv*16+15 for the 16 LDS rows
        int lr = l16;             // A-row / B-col within tile
        int kq = g;               // k subgroup
        f32x4 acc = {0.f, 0.f, 0.f, 0.f};
#pragma unroll
        for (int kg = 0; kg < 4; ++kg) {
            bf16x8 af = *reinterpret_cast<const bf16x8*>(&lds[lr][kg * 16 + kq * 4]);
            bf16x8 bf = *reinterpret_cast<const bf16x8*>(
                Wt + (size_t)(wv * 16 + lr) * NHID + kg * 32 + kq * 8);
            acc = __builtin_amdgcn_mfma_f32_16x16x32_bf16(af, bf, acc, 0, 0, 0);
        }
        int c = wv * 16 + lr;
        float b = bias[c];
#pragma unroll
        for (int e = 0; e < 4; ++e) {
            int r = blockIdx.x * 16 + kq * 4 + e;
            if (r < N) {
                float v = fmaxf(acc[e] + b, 0.f);
                Hout[(size_t)r * NHID + c] = f2bf(v);
            }
        }
    }
}

// plain aggregation (layer 3 front): one wave per node, writes bf16 row
__global__ __launch_bounds__(256) void k_agg(const unsigned int* __restrict__ Hb,
        const int* __restrict__ csr_src, const int* __restrict__ rowptr,
        const int* __restrict__ bsum, const int* __restrict__ cnt,
        const float* __restrict__ dinv, unsigned int* __restrict__ aggb, int N) {
    int w = (blockIdx.x * 256 + threadIdx.x) >> 6;
    if (w >= N) return;
    int lane = threadIdx.x & 63;
    int g = lane >> 4;
    int l16 = lane & 15;
    float diw = dinv[w];
    u32x4 us = reinterpret_cast<const u32x4*>(Hb + (size_t)w * (NHID / 2))[l16];
    float a[8];
#pragma unroll
    for (int e = 0; e < 8; ++e) a[e] = 0.f;
    int beg = rowptr[w] + bsum[w >> 10];
    int deg = cnt[w];
    int end = beg + deg;
    int trips = (deg + 15) >> 4;
    int j = beg + g;
    for (int t = 0; t < trips; ++t, j += 16) {
        int s0 = w, s1 = w, s2 = w, s3 = w;
        if (j < end)      s0 = csr_src[j];
        if (j + 4 < end)  s1 = csr_src[j + 4];
        if (j + 8 < end)  s2 = csr_src[j + 8];
        if (j + 12 < end) s3 = csr_src[j + 12];
        float n0 = (j < end)      ? dinv[s0] * diw : 0.f;
        float n1 = (j + 4 < end)  ? dinv[s1] * diw : 0.f;
        float n2 = (j + 8 < end)  ? dinv[s2] * diw : 0.f;
        float n3 = (j + 12 < end) ? dinv[s3] * diw : 0.f;
        u32x4 u0 = reinterpret_cast<const u32x4*>(Hb + (size_t)s0 * (NHID / 2))[l16];
        u32x4 u1 = reinterpret_cast<const u32x4*>(Hb + (size_t)s1 * (NHID / 2))[l16];
        u32x4 u2 = reinterpret_cast<const u32x4*>(Hb + (size_t)s2 * (NHID / 2))[l16];
        u32x4 u3 = reinterpret_cast<const u32x4*>(Hb + (size_t)s3 * (NHID / 2))[l16];
        fma8(u0, n0, a);
        fma8(u1, n1, a);
        fma8(u2, n2, a);
        fma8(u3, n3, a);
    }
    if (g == 0) fma8(us, diw * diw, a);
#pragma unroll
    for (int e = 0; e < 8; ++e) {
        a[e] += __shfl_xor(a[e], 16);
        a[e] += __shfl_xor(a[e], 32);
    }
    if (g == 0) {
        u32x4 o;
        o[0] = packbf(a[0], a[1]);
        o[1] = packbf(a[2], a[3]);
        o[2] = packbf(a[4], a[5]);
        o[3] = packbf(a[6], a[7]);
        *reinterpret_cast<u32x4*>(aggb + (size_t)w * (NHID / 2) + l16 * 4) = o;
    }
}

// layer-3 GEMM with fused BN (eval) + segment-max epilogue.
__global__ __launch_bounds__(256) void k_gemm_bn(const unsigned short* __restrict__ A,
        const unsigned short* __restrict__ Wt, const float* __restrict__ bias,
        const int* __restrict__ batch, const float* __restrict__ gamma,
        const float* __restrict__ beta, const float* __restrict__ rmean,
        const float* __restrict__ rvar, unsigned int* __restrict__ keys, int M) {
    __shared__ unsigned int smax[64][NHID];   // 32 KB
    __shared__ int bseg[64];
    int tid = threadIdx.x;
    int n0 = blockIdx.x * 64;
    for (int i = tid; i < 64 * NHID; i += 256) ((unsigned int*)smax)[i] = 0u;
    if (tid < 64) {
        int r = n0 + tid;
        bseg[tid] = batch[r < M ? r : M - 1];
    }
    int wave = tid >> 6;
    int lane = tid & 63;
    int lr = lane & 15;
    int kq = lane >> 4;
    int r0 = n0 + wave * 16;
    f32x4 acc[8];
#pragma unroll
    for (int nt = 0; nt < 8; ++nt) acc[nt] = 0.f;
    int ar = r0 + lr;
    bool arok = ar < M;
#pragma unroll
    for (int kg = 0; kg < 4; ++kg) {
        int kb = kg * 32 + kq * 8;
        bf16x8 af = bf16x8(0);
        if (arok) af = *reinterpret_cast<const bf16x8*>(A + (size_t)ar * NHID + kb);
#pragma unroll
        for (int nt = 0; nt < 8; ++nt) {
            bf16x8 bf = *reinterpret_cast<const bf16x8*>(Wt + (size_t)(nt * 16 + lr) * NHID + kb);
            acc[nt] = __builtin_amdgcn_mfma_f32_16x16x32_bf16(af, bf, acc[nt], 0, 0, 0);
        }
    }
    __syncthreads();   // smax/bseg init complete
    int glo = bseg[0];
#pragma unroll
    for (int nt = 0; nt < 8; ++nt) {
        int c = nt * 16 + lr;
        float b = bias[c];
        float sc = gamma[c] * rsqrtf(rvar[c] + 1e-5f);
        float sh = beta[c] - rmean[c] * sc;
#pragma unroll
        for (int e = 0; e < 4; ++e) {
            int rr = wave * 16 + kq * 4 + e;
            if (n0 + rr < M) {
                float v = fmaxf(acc[nt][e] + b, 0.f);
                float y = fmaf(v, sc, sh);
                atomicMax(&smax[bseg[rr] - glo][c], fenc(y));
            }
        }
    }
    __syncthreads();
    int last = M - 1 - n0;
    if (last > 63) last = 63;
    int span = bseg[last] - glo + 1;
    for (int i = tid; i < span * NHID; i += 256) {
        unsigned int v = ((unsigned int*)smax)[i];
        if (v) atomicMax(&keys[(size_t)(glo + (i >> 7)) * NHID + (i & 127)], v);
    }
}

// fused head: decode keys -> relu(G@lw1+lb1) -> relu(@lw2+lb2) -> @lw3+lb3
__global__ __launch_bounds__(128) void k_head(const unsigned int* __restrict__ keys,
        const float* __restrict__ lw1, const float* __restrict__ lb1,
        const float* __restrict__ lw2, const float* __restrict__ lb2,
        const float* __restrict__ lw3, const float* __restrict__ lb3,
        float* __restrict__ out) {
    __shared__ float g0[NHID], g1[NHID], g2[64];
    int r = blockIdx.x;
    int t = threadIdx.x;
    unsigned int u = keys[(size_t)r * NHID + t];
    g0[t] = (u == 0u) ? -3.0e38f : fdec(u);
    __syncthreads();
    float acc = lb1[t];
#pragma unroll 8
    for (int k = 0; k < NHID; ++k) acc = fmaf(g0[k], lw1[k * NHID + t], acc);
    g1[t] = fmaxf(acc, 0.f);
    __syncthreads();
    if (t < 64) {
        acc = lb2[t];
#pragma unroll 8
        for (int k = 0; k < NHID; ++k) acc = fmaf(g1[k], lw2[k * 64 + t], acc);
        g2[t] = fmaxf(acc, 0.f);
    }
    __syncthreads();
    if (t < NCLS) {
        acc = lb3[t];
#pragma unroll 8
        for (int k = 0; k < 64; ++k) acc = fmaf(g2[k], lw3[k * NCLS + t], acc);
        out[(size_t)r * NCLS + t] = acc;
    }
}

extern "C" void kernel_launch(void* const* d_in, const int* in_sizes, int n_in,
                              void* d_out, int out_size, void* d_ws, size_t ws_size,
                              hipStream_t stream) {
    const float* x     = (const float*)d_in[0];
    const int*   ei    = (const int*)d_in[1];
    const int*   batch = (const int*)d_in[2];
    const float* W1 = (const float*)d_in[3];
    const float* b1 = (const float*)d_in[4];
    const float* W2 = (const float*)d_in[5];
    const float* b2 = (const float*)d_in[6];
    const float* W3 = (const float*)d_in[7];
    const float* b3 = (const float*)d_in[8];
    const float* gamma = (const float*)d_in[9];
    const float* beta  = (const float*)d_in[10];
    const float* rmean = (const float*)d_in[11];
    const float* rvar  = (const float*)d_in[12];
    const float* lw1 = (const float*)d_in[13];
    const float* lb1 = (const float*)d_in[14];
    const float* lw2 = (const float*)d_in[15];
    const float* lb2 = (const float*)d_in[16];
    const float* lw3 = (const float*)d_in[17];
    const float* lb3 = (const float*)d_in[18];

    const int N = in_sizes[2];
    const int E = in_sizes[1] / 2;
    const int* src = ei;
    const int* dst = ei + E;

    char* ws = (char*)d_ws;
    size_t off = 0;
    auto alloc = [&](size_t bytes) {
        char* p = ws + off;
        off += (bytes + 255) & ~(size_t)255;
        return p;
    };
    int*   cnt     = (int*)  alloc((size_t)N * 8);     // cnt[N] + cursor[N], one memset
    int*   cursor  = cnt + N;
    int*   rowptr  = (int*)  alloc((size_t)N * 4);
    int*   bsum    = (int*)  alloc(1024 * 4);
    float* dinv    = (float*)alloc((size_t)N * 4);
    int*   csr_src = (int*)  alloc((size_t)E * 4);
    unsigned int* xb   = (unsigned int*)alloc((size_t)N * NHID * 2);
    unsigned int* Hb   = (unsigned int*)alloc((size_t)N * NHID * 2);
    unsigned int* H2   = (unsigned int*)alloc((size_t)N * NHID * 2);
    unsigned short* Wt = (unsigned short*)alloc((size_t)3 * NHID * NHID * 2);
    unsigned int* keys = (unsigned int*)alloc((size_t)NGRAPH * NHID * 4);
    (void)ws_size; (void)n_in; (void)out_size;

    hipMemsetAsync(cnt, 0, (size_t)N * 8, stream);

    int degB = (E + 255) / 256;
    int n8 = N * 16;
    int xB = (n8 + 255) / 256;
    int frontB = degB + xB + 192 + (NGRAPH * NHID + 255) / 256;
    k_front<<<frontB, 256, 0, stream>>>(dst, cnt, E, degB, x, xb, n8, xB,
                                        W1, W2, W3, Wt, keys);
    int nb1 = (N + 1023) / 1024;
    k_scan1<<<nb1, 1024, 0, stream>>>(cnt, dinv, rowptr, bsum, N);
    k_scan2<<<1, 1024, 0, stream>>>(bsum, nb1);
    k_fill<<<degB, 256, 0, stream>>>(src, dst, rowptr, bsum, cursor, csr_src, E);

    int fgb = (N + 15) / 16;                 // fused agg+gemm blocks (16 nodes)
    int ab = ((size_t)N * 64 + 255) / 256;   // plain agg: one wave per node
    int gb = (N + 63) / 64;
    // layer 1: xb -> Hb   (fused)
    k_agg_gemm<<<fgb, 1024, 0, stream>>>(xb, csr_src, rowptr, bsum, cnt, dinv,
                                         Wt, b1, (unsigned short*)Hb, N);
    // layer 2: Hb -> H2   (fused)
    k_agg_gemm<<<fgb, 1024, 0, stream>>>(Hb, csr_src, rowptr, bsum, cnt, dinv,
                                         Wt + 16384, b2, (unsigned short*)H2, N);
    // layer 3: H2 -> Hb (agg), then gemm+bn+segmax
    k_agg<<<ab, 256, 0, stream>>>(H2, csr_src, rowptr, bsum, cnt, dinv, Hb, N);
    k_gemm_bn<<<gb, 256, 0, stream>>>((const unsigned short*)Hb, Wt + 32768, b3,
                                      batch, gamma, beta, rmean, rvar, keys, N);

    k_head<<<NGRAPH, 128, 0, stream>>>(keys, lw1, lb1, lw2, lb2, lw3, lb3, (float*)d_out);
}

// Round 10
// 234.003 us; speedup vs baseline: 1.7448x; 1.0038x over previous
//
#include <hip/hip_runtime.h>
#include <hip/hip_bf16.h>

#define NHID 128
#define NGRAPH 512
#define NCLS 10

typedef __attribute__((ext_vector_type(8))) short bf16x8;
typedef __attribute__((ext_vector_type(4))) float f32x4;
typedef __attribute__((ext_vector_type(4))) unsigned int u32x4;

// order-preserving float<->uint encoding for atomicMax-based segment max
__device__ inline unsigned int fenc(float f) {
    unsigned int u = __float_as_uint(f);
    return (u & 0x80000000u) ? ~u : (u | 0x80000000u);
}
__device__ inline float fdec(unsigned int u) {
    u = (u & 0x80000000u) ? (u & 0x7fffffffu) : ~u;
    return __uint_as_float(u);
}
// f32 -> bf16 round-to-nearest-even (finite inputs)
__device__ inline unsigned short f2bf(float f) {
    unsigned int u = __float_as_uint(f);
    return (unsigned short)((u + 0x7fffu + ((u >> 16) & 1u)) >> 16);
}
__device__ inline unsigned int packbf(float lo, float hi) {
    return (unsigned)f2bf(lo) | ((unsigned)f2bf(hi) << 16);
}

// merged front kernel: deg atomics | x->bf16 | W transpose | keys zero
__global__ void k_front(const int* __restrict__ dst, int* __restrict__ cnt, int E, int degB,
                        const float* __restrict__ x, unsigned int* __restrict__ xb, int n8, int xB,
                        const float* __restrict__ W1, const float* __restrict__ W2,
                        const float* __restrict__ W3, unsigned short* __restrict__ Wt,
                        unsigned int* __restrict__ keys) {
    int b = blockIdx.x;
    if (b < degB) {
        int e = b * 256 + threadIdx.x;
        if (e < E) atomicAdd(&cnt[dst[e]], 1);
    } else if (b < degB + xB) {
        int i = (b - degB) * 256 + threadIdx.x;
        if (i < n8) {
            const float* p = x + (size_t)i * 8;
            f32x4 a = *reinterpret_cast<const f32x4*>(p);
            f32x4 c = *reinterpret_cast<const f32x4*>(p + 4);
            u32x4 o;
            o[0] = packbf(a[0], a[1]);
            o[1] = packbf(a[2], a[3]);
            o[2] = packbf(c[0], c[1]);
            o[3] = packbf(c[2], c[3]);
            *reinterpret_cast<u32x4*>(xb + (size_t)i * 4) = o;
        }
    } else if (b < degB + xB + 192) {
        int idx = (b - degB - xB) * 256 + threadIdx.x;   // < 3*16384
        int l = idx >> 14;
        int r = idx & 16383;
        const float* W = (l == 0) ? W1 : (l == 1) ? W2 : W3;
        int c = r & 127, k = r >> 7;
        Wt[l * 16384 + c * NHID + k] = f2bf(W[k * NHID + c]);
    } else {
        int i = (b - degB - xB - 192) * 256 + threadIdx.x;
        if (i < NGRAPH * NHID) keys[i] = 0u;
    }
}

// phase 1: per-block (1024-wide) scan of cnt; store chunk-local EXCLUSIVE
// prefix at rowptr[i]; block totals into bsum; dinv as a free rider.
__global__ __launch_bounds__(1024) void k_scan1(const int* __restrict__ cnt,
        float* __restrict__ dinv, int* __restrict__ rowptr,
        int* __restrict__ bsum, int N) {
    __shared__ int lds[1024];
    int t = threadIdx.x;
    int i = blockIdx.x * 1024 + t;
    int v = (i < N) ? cnt[i] : 0;
    if (i < N) dinv[i] = rsqrtf((float)v + 1.0f);
    lds[t] = v;
    __syncthreads();
    for (int off = 1; off < 1024; off <<= 1) {
        int x = (t >= off) ? lds[t - off] : 0;
        __syncthreads();
        lds[t] += x;
        __syncthreads();
    }
    if (i < N) rowptr[i] = lds[t] - v;     // exclusive within chunk
    if (t == 1023) bsum[blockIdx.x] = lds[1023];
}

// phase 2: exclusive scan of nb block sums (nb <= 1024), in place
__global__ __launch_bounds__(1024) void k_scan2(int* __restrict__ bsum, int nb) {
    __shared__ int lds[1024];
    int t = threadIdx.x;
    int v = (t < nb) ? bsum[t] : 0;
    lds[t] = v;
    __syncthreads();
    for (int off = 1; off < 1024; off <<= 1) {
        int x = (t >= off) ? lds[t - off] : 0;
        __syncthreads();
        lds[t] += x;
        __syncthreads();
    }
    if (t < nb) bsum[t] = lds[t] - v;
}

// build CSR src list (4B/edge); norms are computed in the gather
__global__ void k_fill(const int* __restrict__ src, const int* __restrict__ dst,
                       const int* __restrict__ rowptr, const int* __restrict__ bsum,
                       int* __restrict__ cursor, int* __restrict__ csr_src, int E) {
    int e = blockIdx.x * blockDim.x + threadIdx.x;
    if (e >= E) return;
    int s = src[e], d = dst[e];
    int pos = rowptr[d] + bsum[d >> 10] + atomicAdd(&cursor[d], 1);
    csr_src[pos] = s;
}

__device__ inline void fma8(const u32x4& u, float nw, float* a) {
#pragma unroll
    for (int q = 0; q < 4; ++q) {
        a[2 * q]     = fmaf(nw, __uint_as_float(u[q] << 16), a[2 * q]);
        a[2 * q + 1] = fmaf(nw, __uint_as_float(u[q] & 0xffff0000u), a[2 * q + 1]);
    }
}

// shared gather phase: one wave per node -> bf16 row in lds[wv][]
__device__ inline void gather_row(const unsigned int* __restrict__ Hin,
        const int* __restrict__ csr_src, const int* __restrict__ rowptr,
        const int* __restrict__ bsum, const int* __restrict__ cnt,
        const float* __restrict__ dinv, unsigned int (*lds)[68],
        int w, int wv, int g, int l16, int N) {
    if (w < N) {
        float diw = dinv[w];
        u32x4 us = reinterpret_cast<const u32x4*>(Hin + (size_t)w * (NHID / 2))[l16];
        float a[8];
#pragma unroll
        for (int e = 0; e < 8; ++e) a[e] = 0.f;
        int beg = rowptr[w] + bsum[w >> 10];
        int deg = cnt[w];
        int end = beg + deg;
        int trips = (deg + 15) >> 4;
        int j = beg + g;
        for (int t = 0; t < trips; ++t, j += 16) {
            int s0 = w, s1 = w, s2 = w, s3 = w;
            if (j < end)      s0 = csr_src[j];
            if (j + 4 < end)  s1 = csr_src[j + 4];
            if (j + 8 < end)  s2 = csr_src[j + 8];
            if (j + 12 < end) s3 = csr_src[j + 12];
            float n0 = (j < end)      ? dinv[s0] * diw : 0.f;
            float n1 = (j + 4 < end)  ? dinv[s1] * diw : 0.f;
            float n2 = (j + 8 < end)  ? dinv[s2] * diw : 0.f;
            float n3 = (j + 12 < end) ? dinv[s3] * diw : 0.f;
            u32x4 u0 = reinterpret_cast<const u32x4*>(Hin + (size_t)s0 * (NHID / 2))[l16];
            u32x4 u1 = reinterpret_cast<const u32x4*>(Hin + (size_t)s1 * (NHID / 2))[l16];
            u32x4 u2 = reinterpret_cast<const u32x4*>(Hin + (size_t)s2 * (NHID / 2))[l16];
            u32x4 u3 = reinterpret_cast<const u32x4*>(Hin + (size_t)s3 * (NHID / 2))[l16];
            fma8(u0, n0, a);
            fma8(u1, n1, a);
            fma8(u2, n2, a);
            fma8(u3, n3, a);
        }
        if (g == 0) fma8(us, diw * diw, a);
#pragma unroll
        for (int e = 0; e < 8; ++e) {
            a[e] += __shfl_xor(a[e], 16);
            a[e] += __shfl_xor(a[e], 32);
        }
        if (g == 0) {
            u32x4 o;
            o[0] = packbf(a[0], a[1]);
            o[1] = packbf(a[2], a[3]);
            o[2] = packbf(a[4], a[5]);
            o[3] = packbf(a[6], a[7]);
            *reinterpret_cast<u32x4*>(&lds[wv][l16 * 4]) = o;
        }
    } else if (g == 0) {
        u32x4 z = {0u, 0u, 0u, 0u};
        *reinterpret_cast<u32x4*>(&lds[wv][l16 * 4]) = z;
    }
}

// Fused aggregate+GEMM (layers 1-2): 1024-thr block = 16 waves, one wave per
// node gather -> LDS tile, barrier, waves 0..7 compute one 16-col MFMA tile.
__global__ __launch_bounds__(1024) void k_agg_gemm(const unsigned int* __restrict__ Hin,
        const int* __restrict__ csr_src, const int* __restrict__ rowptr,
        const int* __restrict__ bsum, const int* __restrict__ cnt,
        const float* __restrict__ dinv, const unsigned short* __restrict__ Wt,
        const float* __restrict__ bias, unsigned short* __restrict__ Hout, int N) {
    __shared__ unsigned int lds[16][68];
    int wv = threadIdx.x >> 6;
    int lane = threadIdx.x & 63;
    int g = lane >> 4;
    int l16 = lane & 15;
    int w = blockIdx.x * 16 + wv;
    gather_row(Hin, csr_src, rowptr, bsum, cnt, dinv, lds, w, wv, g, l16, N);
    __syncthreads();
    if (wv < 8) {
        int lr = l16;
        int kq = g;
        f32x4 acc = {0.f, 0.f, 0.f, 0.f};
#pragma unroll
        for (int kg = 0; kg < 4; ++kg) {
            bf16x8 af = *reinterpret_cast<const bf16x8*>(&lds[lr][kg * 16 + kq * 4]);
            bf16x8 bf = *reinterpret_cast<const bf16x8*>(
                Wt + (size_t)(wv * 16 + lr) * NHID + kg * 32 + kq * 8);
            acc = __builtin_amdgcn_mfma_f32_16x16x32_bf16(af, bf, acc, 0, 0, 0);
        }
        int c = wv * 16 + lr;
        float b = bias[c];
#pragma unroll
        for (int e = 0; e < 4; ++e) {
            int r = blockIdx.x * 16 + kq * 4 + e;
            if (r < N) {
                float v = fmaxf(acc[e] + b, 0.f);
                Hout[(size_t)r * NHID + c] = f2bf(v);
            }
        }
    }
}

// Fused aggregate+GEMM+BN+segment-max (layer 3): same gather/MFMA structure;
// epilogue applies bias+relu+BN, pre-reduces per-block segment max in LDS
// (16 rows, sorted batch -> small span), then flushes encoded atomicMax.
__global__ __launch_bounds__(1024) void k_agg_gemm_bn(const unsigned int* __restrict__ Hin,
        const int* __restrict__ csr_src, const int* __restrict__ rowptr,
        const int* __restrict__ bsum, const int* __restrict__ cnt,
        const float* __restrict__ dinv, const unsigned short* __restrict__ Wt,
        const float* __restrict__ bias, const int* __restrict__ batch,
        const float* __restrict__ gamma, const float* __restrict__ beta,
        const float* __restrict__ rmean, const float* __restrict__ rvar,
        unsigned int* __restrict__ keys, int N) {
    __shared__ unsigned int lds[16][68];
    __shared__ unsigned int smax[16][NHID];   // 8 KB, indexed by local segment
    __shared__ int bseg[16];
    int tid = threadIdx.x;
    int wv = tid >> 6;
    int lane = tid & 63;
    int g = lane >> 4;
    int l16 = lane & 15;
    int n0 = blockIdx.x * 16;
    for (int i = tid; i < 16 * NHID; i += 1024) ((unsigned int*)smax)[i] = 0u;
    if (tid < 16) {
        int r = n0 + tid;
        bseg[tid] = batch[r < N ? r : N - 1];
    }
    int w = n0 + wv;
    gather_row(Hin, csr_src, rowptr, bsum, cnt, dinv, lds, w, wv, g, l16, N);
    __syncthreads();   // lds rows + smax init + bseg ready
    if (wv < 8) {
        int lr = l16;
        int kq = g;
        f32x4 acc = {0.f, 0.f, 0.f, 0.f};
#pragma unroll
        for (int kg = 0; kg < 4; ++kg) {
            bf16x8 af = *reinterpret_cast<const bf16x8*>(&lds[lr][kg * 16 + kq * 4]);
            bf16x8 bf = *reinterpret_cast<const bf16x8*>(
                Wt + (size_t)(wv * 16 + lr) * NHID + kg * 32 + kq * 8);
            acc = __builtin_amdgcn_mfma_f32_16x16x32_bf16(af, bf, acc, 0, 0, 0);
        }
        int c = wv * 16 + lr;
        float b = bias[c];
        float sc = gamma[c] * rsqrtf(rvar[c] + 1e-5f);
        float sh = beta[c] - rmean[c] * sc;
        int glo = bseg[0];
#pragma unroll
        for (int e = 0; e < 4; ++e) {
            int rr = kq * 4 + e;              // row within block
            if (n0 + rr < N) {
                float v = fmaxf(acc[e] + b, 0.f);
                float y = fmaf(v, sc, sh);
                atomicMax(&smax[bseg[rr] - glo][c], fenc(y));
            }
        }
    }
    __syncthreads();
    int glo = bseg[0];
    int last = N - 1 - n0;
    if (last > 15) last = 15;
    int span = bseg[last] - glo + 1;
    for (int i = tid; i < span * NHID; i += 1024) {
        unsigned int v = ((unsigned int*)smax)[i];
        if (v) atomicMax(&keys[(size_t)(glo + (i >> 7)) * NHID + (i & 127)], v);
    }
}

// fused head: decode keys -> relu(G@lw1+lb1) -> relu(@lw2+lb2) -> @lw3+lb3
__global__ __launch_bounds__(128) void k_head(const unsigned int* __restrict__ keys,
        const float* __restrict__ lw1, const float* __restrict__ lb1,
        const float* __restrict__ lw2, const float* __restrict__ lb2,
        const float* __restrict__ lw3, const float* __restrict__ lb3,
        float* __restrict__ out) {
    __shared__ float g0[NHID], g1[NHID], g2[64];
    int r = blockIdx.x;
    int t = threadIdx.x;
    unsigned int u = keys[(size_t)r * NHID + t];
    g0[t] = (u == 0u) ? -3.0e38f : fdec(u);
    __syncthreads();
    float acc = lb1[t];
#pragma unroll 8
    for (int k = 0; k < NHID; ++k) acc = fmaf(g0[k], lw1[k * NHID + t], acc);
    g1[t] = fmaxf(acc, 0.f);
    __syncthreads();
    if (t < 64) {
        acc = lb2[t];
#pragma unroll 8
        for (int k = 0; k < NHID; ++k) acc = fmaf(g1[k], lw2[k * 64 + t], acc);
        g2[t] = fmaxf(acc, 0.f);
    }
    __syncthreads();
    if (t < NCLS) {
        acc = lb3[t];
#pragma unroll 8
        for (int k = 0; k < 64; ++k) acc = fmaf(g2[k], lw3[k * NCLS + t], acc);
        out[(size_t)r * NCLS + t] = acc;
    }
}

extern "C" void kernel_launch(void* const* d_in, const int* in_sizes, int n_in,
                              void* d_out, int out_size, void* d_ws, size_t ws_size,
                              hipStream_t stream) {
    const float* x     = (const float*)d_in[0];
    const int*   ei    = (const int*)d_in[1];
    const int*   batch = (const int*)d_in[2];
    const float* W1 = (const float*)d_in[3];
    const float* b1 = (const float*)d_in[4];
    const float* W2 = (const float*)d_in[5];
    const float* b2 = (const float*)d_in[6];
    const float* W3 = (const float*)d_in[7];
    const float* b3 = (const float*)d_in[8];
    const float* gamma = (const float*)d_in[9];
    const float* beta  = (const float*)d_in[10];
    const float* rmean = (const float*)d_in[11];
    const float* rvar  = (const float*)d_in[12];
    const float* lw1 = (const float*)d_in[13];
    const float* lb1 = (const float*)d_in[14];
    const float* lw2 = (const float*)d_in[15];
    const float* lb2 = (const float*)d_in[16];
    const float* lw3 = (const float*)d_in[17];
    const float* lb3 = (const float*)d_in[18];

    const int N = in_sizes[2];
    const int E = in_sizes[1] / 2;
    const int* src = ei;
    const int* dst = ei + E;

    char* ws = (char*)d_ws;
    size_t off = 0;
    auto alloc = [&](size_t bytes) {
        char* p = ws + off;
        off += (bytes + 255) & ~(size_t)255;
        return p;
    };
    int*   cnt     = (int*)  alloc((size_t)N * 8);     // cnt[N] + cursor[N], one memset
    int*   cursor  = cnt + N;
    int*   rowptr  = (int*)  alloc((size_t)N * 4);
    int*   bsum    = (int*)  alloc(1024 * 4);
    float* dinv    = (float*)alloc((size_t)N * 4);
    int*   csr_src = (int*)  alloc((size_t)E * 4);
    unsigned int* xb   = (unsigned int*)alloc((size_t)N * NHID * 2);
    unsigned int* Hb   = (unsigned int*)alloc((size_t)N * NHID * 2);
    unsigned int* H2   = (unsigned int*)alloc((size_t)N * NHID * 2);
    unsigned short* Wt = (unsigned short*)alloc((size_t)3 * NHID * NHID * 2);
    unsigned int* keys = (unsigned int*)alloc((size_t)NGRAPH * NHID * 4);
    (void)ws_size; (void)n_in; (void)out_size;

    hipMemsetAsync(cnt, 0, (size_t)N * 8, stream);

    int degB = (E + 255) / 256;
    int n8 = N * 16;
    int xB = (n8 + 255) / 256;
    int frontB = degB + xB + 192 + (NGRAPH * NHID + 255) / 256;
    k_front<<<frontB, 256, 0, stream>>>(dst, cnt, E, degB, x, xb, n8, xB,
                                        W1, W2, W3, Wt, keys);
    int nb1 = (N + 1023) / 1024;
    k_scan1<<<nb1, 1024, 0, stream>>>(cnt, dinv, rowptr, bsum, N);
    k_scan2<<<1, 1024, 0, stream>>>(bsum, nb1);
    k_fill<<<degB, 256, 0, stream>>>(src, dst, rowptr, bsum, cursor, csr_src, E);

    int fgb = (N + 15) / 16;                 // fused blocks (16 nodes each)
    // layer 1: xb -> Hb
    k_agg_gemm<<<fgb, 1024, 0, stream>>>(xb, csr_src, rowptr, bsum, cnt, dinv,
                                         Wt, b1, (unsigned short*)Hb, N);
    // layer 2: Hb -> H2
    k_agg_gemm<<<fgb, 1024, 0, stream>>>(Hb, csr_src, rowptr, bsum, cnt, dinv,
                                         Wt + 16384, b2, (unsigned short*)H2, N);
    // layer 3 fused: H2 -> keys (gemm+bn+segmax)
    k_agg_gemm_bn<<<fgb, 1024, 0, stream>>>(H2, csr_src, rowptr, bsum, cnt, dinv,
                                            Wt + 32768, b3, batch, gamma, beta,
                                            rmean, rvar, keys, N);

    k_head<<<NGRAPH, 128, 0, stream>>>(keys, lw1, lb1, lw2, lb2, lw3, lb3, (float*)d_out);
}